// Round 1
// 118.472 us; speedup vs baseline: 1.0071x; 1.0071x over previous
//
#include <hip/hip_runtime.h>
#include <hip/hip_bf16.h>

#define HW 4096
#define CC 64
#define NB 4

typedef short bf16x8 __attribute__((ext_vector_type(8)));
typedef float f32x4 __attribute__((ext_vector_type(4)));

// workspace layout (byte offsets)
#define OFF_F  0                      // bf16 [b][n][8]     262144 B  (f pre-scaled by log2e)
#define OFF_G  262144                 // bf16 [b][n][8]     262144 B
#define OFF_H  524288                 // bf16 [b][c][n]    2097152 B
#define OFF_ZP 2621440                // f32  [b][n][4]     262144 B  (partial softmax denoms)
#define OFF_O  2883584                // bf16 [4hx][b][c][m] 8388608 B
// total ~11.27 MB

__device__ __forceinline__ float bf2f(short s) {
    unsigned u = ((unsigned)(unsigned short)s) << 16;
    return __uint_as_float(u);
}

// 2^x via raw v_exp_f32 (f is pre-scaled by log2e so exp(f.g) == exp2(f'.g);
// saves the v_mul that __expf emits). ~100M exps in this op => ~1.3us of muls.
__device__ __forceinline__ float e2(float x) {
#if __has_builtin(__builtin_amdgcn_exp2f)
    return __builtin_amdgcn_exp2f(x);
#else
    return exp2f(x);
#endif
}

#define LOG2E 1.44269504088896340736f

// ---------------------------------------------------------------------------
// Kernel 1 (MFMA): Y[80,64] = W_all @ X[64,64npix] + bias, per 64-pixel tile.
// W A-fragments live in registers. Wf/bf rows are PRE-SCALED by log2e so all
// downstream exp() become a single v_exp_f32.
// ---------------------------------------------------------------------------
__global__ __launch_bounds__(256) void k_prep(
    const float* __restrict__ x,
    const float* __restrict__ Wf, const float* __restrict__ bf,
    const float* __restrict__ Wg, const float* __restrict__ bg,
    const float* __restrict__ Wh, const float* __restrict__ bh,
    __hip_bfloat16* __restrict__ fb, __hip_bfloat16* __restrict__ gb,
    __hip_bfloat16* __restrict__ hb)
{
    __shared__ __align__(16) __hip_bfloat16 xT[64 * 72];   // [n][c], stride 72
    __shared__ __align__(16) __hip_bfloat16 fgT[64 * 24];  // [n][16 rows], stride 24

    const int b  = blockIdx.y;
    const int n0 = blockIdx.x * 64;
    const int tid = (int)threadIdx.x;
    const int w = tid >> 6, lane = tid & 63, quad = lane >> 4, l15 = lane & 15;

    // ---- stage xT[n][c] (bf16): thread owns n=lane, c-pairs {w,w+4,...} ----
    {
        const int n = lane;
        const float* xb = x + (size_t)b * (CC * HW) + n0 + n;
#pragma unroll
        for (int i = 0; i < 8; ++i) {
            const int c = (w + 4 * i) * 2;
            const float v0 = xb[(size_t)c * HW];
            const float v1 = xb[(size_t)(c + 1) * HW];
            __hip_bfloat16 t[2] = {__float2bfloat16(v0), __float2bfloat16(v1)};
            *reinterpret_cast<unsigned*>(&xT[n * 72 + c]) =
                *reinterpret_cast<const unsigned*>(t);
        }
    }

    // ---- W A-fragments in registers: wa[mt][kk], row = mt*16 + l15 ----
    bf16x8 wa[5][2];
#pragma unroll
    for (int mt = 0; mt < 5; ++mt) {
        const int row = mt * 16 + l15;
        const float* src = (row < 8) ? (Wf + row * 64)
                         : (row < 16) ? (Wg + (row - 8) * 64)
                                      : (Wh + (row - 16) * 64);
        const float sc = (row < 8) ? LOG2E : 1.0f;   // fold log2e into f
#pragma unroll
        for (int kk = 0; kk < 2; ++kk) {
            const float4 a = *(const float4*)(src + kk * 32 + quad * 8);
            const float4 c4 = *(const float4*)(src + kk * 32 + quad * 8 + 4);
            __hip_bfloat16 t[8];
            t[0] = __float2bfloat16(a.x * sc);  t[1] = __float2bfloat16(a.y * sc);
            t[2] = __float2bfloat16(a.z * sc);  t[3] = __float2bfloat16(a.w * sc);
            t[4] = __float2bfloat16(c4.x * sc); t[5] = __float2bfloat16(c4.y * sc);
            t[6] = __float2bfloat16(c4.z * sc); t[7] = __float2bfloat16(c4.w * sc);
            wa[mt][kk] = *reinterpret_cast<const bf16x8*>(t);
        }
    }

    // ---- bias into accumulators: D row = quad*4 + r ----
    f32x4 acc[5];
#pragma unroll
    for (int mt = 0; mt < 5; ++mt) {
#pragma unroll
        for (int r = 0; r < 4; ++r) {
            const int grow = mt * 16 + quad * 4 + r;
            acc[mt][r] = (grow < 8) ? bf[grow] * LOG2E
                       : (grow < 16) ? bg[grow - 8]
                                     : bh[grow - 16];
        }
    }

    __syncthreads();

    // ---- B-fragments (wave w owns pixels n0 + w*16 + l15) and MFMA ----
    const bf16x8 b0 = *(const bf16x8*)&xT[(w * 16 + l15) * 72 + quad * 8];
    const bf16x8 b1 = *(const bf16x8*)&xT[(w * 16 + l15) * 72 + 32 + quad * 8];
#pragma unroll
    for (int mt = 0; mt < 5; ++mt) {
        acc[mt] = __builtin_amdgcn_mfma_f32_16x16x32_bf16(wa[mt][0], b0, acc[mt], 0, 0, 0);
        acc[mt] = __builtin_amdgcn_mfma_f32_16x16x32_bf16(wa[mt][1], b1, acc[mt], 0, 0, 0);
    }

    // ---- h rows (mt 1..4) direct: hb[b][hrow][n0 + w*16 + l15] ----
#pragma unroll
    for (int mt = 1; mt < 5; ++mt) {
#pragma unroll
        for (int r = 0; r < 4; ++r) {
            const int hrow = (mt - 1) * 16 + quad * 4 + r;
            hb[((size_t)(b * 64 + hrow)) * HW + n0 + w * 16 + l15] =
                __float2bfloat16(acc[0 + mt][r]);
        }
    }

    // ---- f/g rows (mt 0): transpose via LDS then coalesced float4 stores ----
#pragma unroll
    for (int r = 0; r < 4; r += 2) {
        __hip_bfloat16 t[2] = {__float2bfloat16(acc[0][r]),
                               __float2bfloat16(acc[0][r + 1])};
        *reinterpret_cast<unsigned*>(&fgT[(w * 16 + l15) * 24 + quad * 4 + r]) =
            *reinterpret_cast<const unsigned*>(t);
    }
    __syncthreads();
    if (tid < 64) {
        const size_t bn = (size_t)b * HW + n0 + tid;
        *(float4*)(fb + bn * 8) = *(const float4*)&fgT[tid * 24];
    } else if (tid < 128) {
        const int n = tid - 64;
        const size_t bn = (size_t)b * HW + n0 + n;
        *(float4*)(gb + bn * 8) = *(const float4*)&fgT[n * 24 + 8];
    }
}

// ---------------------------------------------------------------------------
// Kernel 2: partial softmax denominators.
// Old version: 256 blocks = 1 wave/SIMD, 64KB LDS stage, VALU(exp)-bound with
// zero latency hiding. Now: i-dim split 4-way (grid 64 x 4b x 4is), each block
// stages a 16KB f-slice and emits zpart[b][n][is] = sum_{i in slice} 2^(f_i.g_n).
// 1024 blocks -> 4 waves/SIMD; k_attn combines the 4 partials + rcp.
// ---------------------------------------------------------------------------
__global__ __launch_bounds__(256) void k_z(
    const __hip_bfloat16* __restrict__ fb, const __hip_bfloat16* __restrict__ gb,
    float* __restrict__ zpart)
{
    __shared__ __align__(16) __hip_bfloat16 fS[1024 * 8];   // 16 KB slice
    __shared__ __align__(16) __hip_bfloat16 gS[64 * 8];
    __shared__ float zred[4][64];

    const int nt = blockIdx.x, b = blockIdx.y, is = blockIdx.z;
    const int n0 = nt * 64, i0 = is * 1024;
    const int tid = (int)threadIdx.x;
    const int w = tid >> 6, lane = tid & 63, quad = lane >> 4, l15 = lane & 15;

    const float4* fsrc = (const float4*)(fb + ((size_t)b * HW + i0) * 8);
#pragma unroll
    for (int q = 0; q < 4; ++q)
        ((float4*)fS)[q * 256 + tid] = fsrc[q * 256 + tid];
    if (tid < 64)
        *(float4*)&gS[tid * 8] = *(const float4*)(gb + ((size_t)b * HW + n0 + tid) * 8);
    __syncthreads();

    const f32x4 cz = {0.f, 0.f, 0.f, 0.f};
    bf16x8 bgf[4];
#pragma unroll
    for (int ns = 0; ns < 4; ++ns) {
        bf16x8 v = {0, 0, 0, 0, 0, 0, 0, 0};
        if (quad == 0) v = *(const bf16x8*)&gS[(ns * 16 + l15) * 8];
        bgf[ns] = v;
    }

    float z[4] = {0.f, 0.f, 0.f, 0.f};
    for (int it = 0; it < 16; ++it) {
        const int i = it * 64 + w * 16;
        bf16x8 afr = {0, 0, 0, 0, 0, 0, 0, 0};
        if (quad == 0) afr = *(const bf16x8*)&fS[(i + l15) * 8];
#pragma unroll
        for (int ns = 0; ns < 4; ++ns) {
            f32x4 s = __builtin_amdgcn_mfma_f32_16x16x32_bf16(afr, bgf[ns], cz, 0, 0, 0);
            z[ns] += e2(s[0]) + e2(s[1]) + e2(s[2]) + e2(s[3]);
        }
    }

#pragma unroll
    for (int ns = 0; ns < 4; ++ns) {
        float v = z[ns];
        v += __shfl_xor(v, 16);
        v += __shfl_xor(v, 32);
        if (quad == 0) zred[w][ns * 16 + l15] = v;
    }
    __syncthreads();
    if (tid < 64) {
        const float s = zred[0][tid] + zred[1][tid] + zred[2][tid] + zred[3][tid];
        zpart[((size_t)b * HW + n0 + tid) * 4 + is] = s;
    }
}

// ---------------------------------------------------------------------------
// Kernel 3: attention. Per 64n-chunk: MFMA s-tile (SWAPPED operands so the
// s-tile lands transposed: lane holds 4 CONSECUTIVE n at one m-row -> the
// exp/mask/pT path packs into one ds_write_b64 instead of 4 ds_write_b16,
// and zinv arrives as one broadcast f32x4), p = 2^s * zinv (+tri mask),
// P->LDS bf16, MFMA P x H. Register-prefetch of next chunk overlaps VMEM.
// NO atomics: each (hx,b,mt) block stores its own bf16 partial tile.
// ---------------------------------------------------------------------------
__global__ __launch_bounds__(256) void k_attn(
    const __hip_bfloat16* __restrict__ fb, const __hip_bfloat16* __restrict__ gb,
    const __hip_bfloat16* __restrict__ hb, const float* __restrict__ zpart,
    __hip_bfloat16* __restrict__ opart)
{
    __shared__ __align__(16) __hip_bfloat16 gS[64 * 8];
    __shared__ __align__(16) float zS[64];
    __shared__ __align__(16) __hip_bfloat16 hT[64 * 72];
    __shared__ __align__(16) __hip_bfloat16 pT[64 * 72];

    const int hx = blockIdx.x;               // 0..3 n-split
    const int b  = blockIdx.y;
    const int r  = blockIdx.z;
    const int mt = (r < 32) ? r : 95 - r;    // fold for load balance
    const int m0 = mt * 64;
    const int tid = (int)threadIdx.x;
    const int w = tid >> 6, lane = tid & 63, quad = lane >> 4, l15 = lane & 15;

    // hT staging coords for this thread (2 float4 = 32 B of the 8 KB tile)
    const int c0s = tid >> 3,          ch0 = tid & 7;
    const int c1s = (256 + tid) >> 3,  ch1 = (256 + tid) & 7;

    const f32x4 cz = {0.f, 0.f, 0.f, 0.f};

    bf16x8 af = {0, 0, 0, 0, 0, 0, 0, 0};
    if (quad == 0)
        af = *(const bf16x8*)(fb + ((size_t)b * HW + m0 + w * 16 + l15) * 8);

    f32x4 accO[4];
#pragma unroll
    for (int i = 0; i < 4; ++i) accO[i] = cz;

    const int nc0 = mt + hx;
    float4 hv0 = make_float4(0.f, 0.f, 0.f, 0.f);
    float4 hv1 = hv0, gv = hv0, zv = hv0;
    if (nc0 < 64) {   // prefetch first chunk
        const int n0 = nc0 * 64;
        hv0 = *(const float4*)(hb + ((size_t)(b * 64 + c0s)) * HW + n0 + ch0 * 8);
        hv1 = *(const float4*)(hb + ((size_t)(b * 64 + c1s)) * HW + n0 + ch1 * 8);
        if (tid < 64) {
            gv = *(const float4*)(gb + ((size_t)b * HW + n0 + tid) * 8);
            zv = *(const float4*)(zpart + ((size_t)b * HW + n0 + tid) * 4);
        }
    }

    for (int nc = nc0; nc < 64; nc += 4) {
        __syncthreads();   // previous phase-B LDS reads complete
        *(float4*)&hT[c0s * 72 + ch0 * 8] = hv0;
        *(float4*)&hT[c1s * 72 + ch1 * 8] = hv1;
        if (tid < 64) {
            *(float4*)&gS[tid * 8] = gv;
            zS[tid] = 1.0f / (zv.x + zv.y + zv.z + zv.w);
        }

        const int nn = nc + 4;
        if (nn < 64) {     // prefetch next chunk while computing this one
            const int n1 = nn * 64;
            hv0 = *(const float4*)(hb + ((size_t)(b * 64 + c0s)) * HW + n1 + ch0 * 8);
            hv1 = *(const float4*)(hb + ((size_t)(b * 64 + c1s)) * HW + n1 + ch1 * 8);
            if (tid < 64) {
                gv = *(const float4*)(gb + ((size_t)b * HW + n1 + tid) * 8);
                zv = *(const float4*)(zpart + ((size_t)b * HW + n1 + tid) * 4);
            }
        }
        __syncthreads();

        const int n0 = nc * 64;
        const bool diag = (nc == mt);
        // ---- phase A (swapped): s^T = g.f^T; lane owns rows n=quad*4+j, col m=l15.
        //      p = 2^s * zinv[n]; tri mask; packed 8B store into pT[m][n].
#pragma unroll
        for (int ns = 0; ns < 4; ++ns) {
            bf16x8 ag = {0, 0, 0, 0, 0, 0, 0, 0};
            if (quad == 0) ag = *(const bf16x8*)&gS[(ns * 16 + l15) * 8];
            f32x4 s = __builtin_amdgcn_mfma_f32_16x16x32_bf16(ag, af, cz, 0, 0, 0);
            const f32x4 ziv = *(const f32x4*)&zS[ns * 16 + quad * 4];   // broadcast per quad
            __hip_bfloat16 t[4];
#pragma unroll
            for (int j = 0; j < 4; ++j) {
                float p = e2(s[j]) * ziv[j];
                if (diag) {
                    const int n = n0 + ns * 16 + quad * 4 + j;
                    const int m = m0 + w * 16 + l15;
                    if (n < m) p = 0.f;
                }
                t[j] = __float2bfloat16(p);
            }
            *(float2*)&pT[(w * 16 + l15) * 72 + ns * 16 + quad * 4] =
                *(const float2*)t;
        }
        // ---- phase B: accO += P x H ----
#pragma unroll
        for (int kb = 0; kb < 2; ++kb) {
            const bf16x8 ap =
                *(const bf16x8*)&pT[(w * 16 + l15) * 72 + kb * 32 + quad * 8];
#pragma unroll
            for (int cs = 0; cs < 4; ++cs) {
                const bf16x8 bh2 =
                    *(const bf16x8*)&hT[(cs * 16 + l15) * 72 + kb * 32 + quad * 8];
                accO[cs] = __builtin_amdgcn_mfma_f32_16x16x32_bf16(ap, bh2, accO[cs], 0, 0, 0);
            }
        }
    }

    // ---- epilogue: coalesced bf16 partial store, opart[hx][b][c][m] ----
#pragma unroll
    for (int cs = 0; cs < 4; ++cs) {
        const int c = cs * 16 + l15;
        __hip_bfloat16 tmp[4];
#pragma unroll
        for (int j = 0; j < 4; ++j) tmp[j] = __float2bfloat16(accO[cs][j]);
        *(float2*)(opart + ((size_t)((hx * NB + b) * 64 + c)) * HW + m0 + w * 16 + quad * 4) =
            *(const float2*)tmp;
    }
}

// ---------------------------------------------------------------------------
// Kernel 4: y = gamma * (sum of 4 partials) + x   (8 floats per thread)
// ---------------------------------------------------------------------------
__global__ __launch_bounds__(256) void k_epi(
    const __hip_bfloat16* __restrict__ opart, const float* __restrict__ x,
    const float* __restrict__ gamma, float* __restrict__ y)
{
    const int t = blockIdx.x * 256 + (int)threadIdx.x;   // 131,072 threads
    const size_t e0 = (size_t)t * 8;
    const float ga = gamma[0];

    float acc[8] = {0, 0, 0, 0, 0, 0, 0, 0};
#pragma unroll
    for (int h = 0; h < 4; ++h) {
        const bf16x8 v = *(const bf16x8*)(opart + (size_t)h * (NB * CC * HW) + e0);
#pragma unroll
        for (int k = 0; k < 8; ++k) acc[k] += bf2f(v[k]);
    }
    const float4 x0 = *(const float4*)(x + e0);
    const float4 x1 = *(const float4*)(x + e0 + 4);
    float4 y0, y1;
    y0.x = ga * acc[0] + x0.x; y0.y = ga * acc[1] + x0.y;
    y0.z = ga * acc[2] + x0.z; y0.w = ga * acc[3] + x0.w;
    y1.x = ga * acc[4] + x1.x; y1.y = ga * acc[5] + x1.y;
    y1.z = ga * acc[6] + x1.z; y1.w = ga * acc[7] + x1.w;
    *(float4*)(y + e0) = y0;
    *(float4*)(y + e0 + 4) = y1;
}

extern "C" void kernel_launch(void* const* d_in, const int* in_sizes, int n_in,
                              void* d_out, int out_size, void* d_ws, size_t ws_size,
                              hipStream_t stream)
{
    const float* x     = (const float*)d_in[0];
    const float* Wf    = (const float*)d_in[1];
    const float* bf    = (const float*)d_in[2];
    const float* Wg    = (const float*)d_in[3];
    const float* bg    = (const float*)d_in[4];
    const float* Wh    = (const float*)d_in[5];
    const float* bh    = (const float*)d_in[6];
    const float* gamma = (const float*)d_in[7];

    char* ws = (char*)d_ws;
    __hip_bfloat16* fb = (__hip_bfloat16*)(ws + OFF_F);
    __hip_bfloat16* gb = (__hip_bfloat16*)(ws + OFF_G);
    __hip_bfloat16* hb = (__hip_bfloat16*)(ws + OFF_H);
    float* zpart = (float*)(ws + OFF_ZP);
    __hip_bfloat16* opart = (__hip_bfloat16*)(ws + OFF_O);
    float* y = (float*)d_out;

    k_prep<<<dim3(64, 4), 256, 0, stream>>>(x, Wf, bf, Wg, bg, Wh, bh, fb, gb, hb);
    k_z<<<dim3(64, 4, 4), 256, 0, stream>>>(fb, gb, zpart);
    k_attn<<<dim3(4, 4, 64), 256, 0, stream>>>(fb, gb, hb, zpart, opart);
    k_epi<<<512, 256, 0, stream>>>(opart, x, gamma, y);
}